// Round 7
// baseline (1163.595 us; speedup 1.0000x reference)
//
#include <hip/hip_runtime.h>

#define N_NODESC 50000
#define N_PAD 50176          // 392 * 128
#define N_EDGESC 800000
#define N_GRAPHSC 128
#define EMBEDC 256
#define MTILES 392

typedef __attribute__((ext_vector_type(8))) _Float16 hf8;
typedef __attribute__((ext_vector_type(4))) float fx4;

__device__ __forceinline__ float h2f(unsigned short u) {
  _Float16 h = *(_Float16*)&u;
  return (float)h;
}
__device__ __forceinline__ unsigned short f2h(float f) {
  _Float16 h = (_Float16)f;
  return *(unsigned short*)&h;
}
__device__ __forceinline__ unsigned int packh2(float lo, float hi) {
  return (unsigned int)f2h(lo) | ((unsigned int)f2h(hi) << 16);
}

// ---------------------------------------------------------------- atom encoder
__global__ __launch_bounds__(256) void atom_encode_k(
    const int* __restrict__ nfeat, const float* __restrict__ atom_emb,
    unsigned short* __restrict__ h16)
{
  int w = threadIdx.x >> 6, lane = threadIdx.x & 63;
  int n = blockIdx.x * 4 + w;
  if (n >= N_NODESC) return;
  const int* nf = nfeat + n * 9;
  float ax = 0.f, ay = 0.f, az = 0.f, aw = 0.f;
#pragma unroll
  for (int c = 0; c < 9; ++c) {
    int idx = nf[c];
    const float4* row = (const float4*)(atom_emb + (c * 128 + idx) * EMBEDC);
    float4 v = row[lane];
    ax += v.x; ay += v.y; az += v.z; aw += v.w;
  }
  ushort4 o;
  o.x = f2h(ax); o.y = f2h(ay); o.z = f2h(az); o.w = f2h(aw);
  *(ushort4*)(h16 + (long)n * 256 + lane * 4) = o;
}

// ---------------------------------------------------------------- degree count
__global__ __launch_bounds__(256) void deg_k(
    const int* __restrict__ dst, int* __restrict__ degs)
{
  int e = blockIdx.x * 256 + threadIdx.x;
  if (e >= N_EDGESC) return;
  atomicAdd(&degs[dst[e]], 1);
}

// ---------------------------------------------------------------- exclusive scan
__global__ __launch_bounds__(1024) void scan_k(
    const int* __restrict__ deg, int* __restrict__ row_start, int n)
{
  __shared__ int buf[1024];
  __shared__ int carry;
  int t = threadIdx.x;
  if (t == 0) carry = 0;
  __syncthreads();
  for (int base = 0; base < n; base += 8192) {
    int loc[8];
    int s = 0;
    int idx0 = base + t * 8;
#pragma unroll
    for (int i = 0; i < 8; ++i) {
      int v = (idx0 + i < n) ? deg[idx0 + i] : 0;
      loc[i] = v; s += v;
    }
    buf[t] = s;
    __syncthreads();
    for (int off = 1; off < 1024; off <<= 1) {
      int add = (t >= off) ? buf[t - off] : 0;
      __syncthreads();
      buf[t] += add;
      __syncthreads();
    }
    int excl = buf[t] - s;
    int run = carry + excl;
#pragma unroll
    for (int i = 0; i < 8; ++i) {
      if (idx0 + i < n) row_start[idx0 + i] = run;
      run += loc[i];
    }
    __syncthreads();
    if (t == 1023) carry += buf[1023];
    __syncthreads();
  }
  if (t == 0) row_start[n] = carry;
}

// ---------------------------------------------------------------- CSR scatter
__global__ __launch_bounds__(256) void scatter_k(
    const int* __restrict__ src, const int* __restrict__ dst,
    const int* __restrict__ row_start, int* __restrict__ fill,
    int* __restrict__ csrc, int* __restrict__ ceid)
{
  int e = blockIdx.x * 256 + threadIdx.x;
  if (e >= N_EDGESC) return;
  int d = dst[e];
  int pos = row_start[d] + atomicAdd(&fill[d], 1);
  csrc[pos] = src[e];
  ceid[pos] = e;
}

// ------------------------------------------ per-node edge-feature histogram
__global__ __launch_bounds__(256) void cnt_k(
    const int* __restrict__ ceid, const int* __restrict__ row_start,
    const int* __restrict__ efeat, int* __restrict__ cnt)
{
  __shared__ int lc[256 * 25];
  int t = threadIdx.x;
  int n = blockIdx.x * 256 + t;
  int base = t * 25;
#pragma unroll
  for (int j = 0; j < 24; ++j) lc[base + j] = 0;
  if (n >= N_NODESC) return;
  int s0 = row_start[n], s1 = row_start[n + 1];
  for (int e = s0; e < s1; ++e) {
    int eid = ceid[e];
    int v0 = efeat[eid * 3 + 0];
    int v1 = efeat[eid * 3 + 1];
    int v2 = efeat[eid * 3 + 2];
    lc[base + v0]++;
    lc[base + 8 + v1]++;
    lc[base + 16 + v2]++;
  }
#pragma unroll
  for (int j = 0; j < 24; ++j) cnt[n * 24 + j] = lc[base + j];
}

// ------------------------------------------------ W transpose + fp16 convert
__global__ __launch_bounds__(256) void wprep_k(
    const float* __restrict__ W, unsigned short* __restrict__ Wt)
{
  int tid = blockIdx.x * 256 + threadIdx.x;     // 5*65536
  int l = tid >> 16, r = tid & 65535;
  int n = r >> 8, k = r & 255;
  float w = W[(long)l * 65536 + k * 256 + n];
  Wt[tid] = f2h(w);                             // tid == l*65536 + n*256 + k
}

// ---------------------------------------------------------------- aggregation
// wave = 1 node; half-wave (32 lanes x 16B) covers a full 512B row.
// half 0 owns edges [s0, s0+ceil(d/2)) + self, half 1 owns the rest (edge
// order within a CSR row is arbitrary, so contiguous split is valid).
// FUSE_BN: gathered rows are pre-BN Y16; apply relu(y*sc+sh) inline (fp32).
template<int FUSE_BN>
__device__ __forceinline__ void bnacc(const uint4 u, float* a,
                                      const float* sc, const float* sh)
{
  unsigned int ws[4] = {u.x, u.y, u.z, u.w};
#pragma unroll
  for (int q = 0; q < 4; ++q) {
    float v0 = h2f((unsigned short)(ws[q] & 0xFFFF));
    float v1 = h2f((unsigned short)(ws[q] >> 16));
    if (FUSE_BN) {
      v0 = fmaxf(0.f, v0 * sc[2 * q] + sh[2 * q]);
      v1 = fmaxf(0.f, v1 * sc[2 * q + 1] + sh[2 * q + 1]);
    }
    a[2 * q] += v0;
    a[2 * q + 1] += v1;
  }
}

template<int FUSE_BN>
__global__ __launch_bounds__(256) void aggregate_t(
    const unsigned short* __restrict__ src16, const float* __restrict__ emb_l,
    const int* __restrict__ csrc, const int* __restrict__ row_start,
    const int* __restrict__ cnt, const float* __restrict__ scale,
    const float* __restrict__ shiftv, unsigned short* __restrict__ X16)
{
  __shared__ unsigned short semb[24 * EMBEDC];   // fp16, 12.3 KB
  for (int i = threadIdx.x; i < 24 * 128; i += 256) {
    float2 f = *(const float2*)&emb_l[i * 2];
    *(unsigned int*)&semb[i * 2] = packh2(f.x, f.y);
  }
  __syncthreads();
  int w = threadIdx.x >> 6, lane = threadIdx.x & 63;
  int n = blockIdx.x * 4 + w;          // 12500*4 == 50000 exactly
  int half = lane >> 5;
  int c8 = (lane & 31) * 8;
  float sc[8], sh[8];
  if (FUSE_BN) {
#pragma unroll
    for (int k = 0; k < 8; ++k) { sc[k] = scale[c8 + k]; sh[k] = shiftv[c8 + k]; }
  }
  float a[8] = {0.f, 0.f, 0.f, 0.f, 0.f, 0.f, 0.f, 0.f};
  int s0 = row_start[n], s1 = row_start[n + 1];
  int d = s1 - s0;
  int dh0 = (d + 1) >> 1;
  int e = half ? (s0 + dh0) : s0;
  int rhi = half ? s1 : (s0 + dh0);
  if (half == 0) {                     // self row
    uint4 u = *(const uint4*)(src16 + (long)n * 256 + c8);
    bnacc<FUSE_BN>(u, a, sc, sh);
  }
  for (; e + 7 < rhi; e += 8) {
    int i0 = csrc[e],     i1 = csrc[e + 1], i2 = csrc[e + 2], i3 = csrc[e + 3];
    int i4 = csrc[e + 4], i5 = csrc[e + 5], i6 = csrc[e + 6], i7 = csrc[e + 7];
    uint4 u0 = *(const uint4*)(src16 + (long)i0 * 256 + c8);
    uint4 u1 = *(const uint4*)(src16 + (long)i1 * 256 + c8);
    uint4 u2 = *(const uint4*)(src16 + (long)i2 * 256 + c8);
    uint4 u3 = *(const uint4*)(src16 + (long)i3 * 256 + c8);
    uint4 u4 = *(const uint4*)(src16 + (long)i4 * 256 + c8);
    uint4 u5 = *(const uint4*)(src16 + (long)i5 * 256 + c8);
    uint4 u6 = *(const uint4*)(src16 + (long)i6 * 256 + c8);
    uint4 u7 = *(const uint4*)(src16 + (long)i7 * 256 + c8);
    bnacc<FUSE_BN>(u0, a, sc, sh); bnacc<FUSE_BN>(u1, a, sc, sh);
    bnacc<FUSE_BN>(u2, a, sc, sh); bnacc<FUSE_BN>(u3, a, sc, sh);
    bnacc<FUSE_BN>(u4, a, sc, sh); bnacc<FUSE_BN>(u5, a, sc, sh);
    bnacc<FUSE_BN>(u6, a, sc, sh); bnacc<FUSE_BN>(u7, a, sc, sh);
  }
  if (e + 3 < rhi) {
    int i0 = csrc[e], i1 = csrc[e + 1], i2 = csrc[e + 2], i3 = csrc[e + 3];
    uint4 u0 = *(const uint4*)(src16 + (long)i0 * 256 + c8);
    uint4 u1 = *(const uint4*)(src16 + (long)i1 * 256 + c8);
    uint4 u2 = *(const uint4*)(src16 + (long)i2 * 256 + c8);
    uint4 u3 = *(const uint4*)(src16 + (long)i3 * 256 + c8);
    bnacc<FUSE_BN>(u0, a, sc, sh); bnacc<FUSE_BN>(u1, a, sc, sh);
    bnacc<FUSE_BN>(u2, a, sc, sh); bnacc<FUSE_BN>(u3, a, sc, sh);
    e += 4;
  }
  for (; e < rhi; ++e) {
    uint4 u = *(const uint4*)(src16 + (long)csrc[e] * 256 + c8);
    bnacc<FUSE_BN>(u, a, sc, sh);
  }
  // combine halves (lane l and l^32 hold the same 8 columns)
#pragma unroll
  for (int k = 0; k < 8; ++k) a[k] += __shfl_xor(a[k], 32);
  const int* cn = cnt + n * 24;
#pragma unroll
  for (int j = 0; j < 24; ++j) {
    int cj = cn[j];
    if (cj) {
      float fc = (float)cj;
      uint4 up = *(const uint4*)&semb[j * EMBEDC + c8];   // 16B/lane, conflict-free
      unsigned int wsv[4] = {up.x, up.y, up.z, up.w};
#pragma unroll
      for (int q = 0; q < 4; ++q) {
        a[2 * q]     += fc * h2f((unsigned short)(wsv[q] & 0xFFFF));
        a[2 * q + 1] += fc * h2f((unsigned short)(wsv[q] >> 16));
      }
    }
  }
  if (half == 0) {
    float inv = 1.0f / (float)(d + 1);
    uint4 o;
    o.x = packh2(a[0] * inv, a[1] * inv);
    o.y = packh2(a[2] * inv, a[3] * inv);
    o.z = packh2(a[4] * inv, a[5] * inv);
    o.w = packh2(a[6] * inv, a[7] * inv);
    *(uint4*)(X16 + (long)n * 256 + c8) = o;
  }
}

// ---------------------------------------------------------------- MFMA GEMM fp16
// Y16 = fp16(X @ W + b) ; per-block BN partials from fp32 accs (no atomics)
__global__ __launch_bounds__(256) void gemm_k(
    const unsigned short* __restrict__ X16, const unsigned short* __restrict__ Bt,
    const float* __restrict__ bl, unsigned short* __restrict__ Y16,
    float* __restrict__ Pp)
{
  __shared__ unsigned short As[128 * 72];
  __shared__ unsigned short Bs[128 * 72];
  __shared__ float red_s[256];
  __shared__ float red_q[256];

  int t = threadIdx.x;
  int bm = blockIdx.x, bn = blockIdx.y;
  int row0 = bm * 128, nc0 = bn * 128;
  int w = t >> 6, l = t & 63;
  int wr = w >> 1, wc = w & 1;
  int lr = l & 15, lk = l >> 4;

  fx4 acc[4][4];
#pragma unroll
  for (int i = 0; i < 4; ++i)
#pragma unroll
    for (int j = 0; j < 4; ++j) acc[i][j] = (fx4){0.f, 0.f, 0.f, 0.f};

  for (int kc = 0; kc < 256; kc += 64) {
    __syncthreads();
#pragma unroll
    for (int q = 0; q < 2; ++q) {
      int id = q * 256 + t;
      int r = id >> 2, c8 = (id & 3) * 16;
      long gA = (long)(row0 + r) * 256 + kc + c8;
      long gB = (long)(nc0 + r) * 256 + kc + c8;
      *(uint4*)&As[r * 72 + c8] = *(const uint4*)(X16 + gA);
      *(uint4*)&As[r * 72 + c8 + 8] = *(const uint4*)(X16 + gA + 8);
      *(uint4*)&Bs[r * 72 + c8] = *(const uint4*)(Bt + gB);
      *(uint4*)&Bs[r * 72 + c8 + 8] = *(const uint4*)(Bt + gB + 8);
    }
    __syncthreads();
#pragma unroll
    for (int ks = 0; ks < 2; ++ks) {
      int ko = ks * 32 + lk * 8;
      hf8 af[4], bf[4];
#pragma unroll
      for (int f = 0; f < 4; ++f) {
        af[f] = *(const hf8*)&As[(wr * 64 + f * 16 + lr) * 72 + ko];
        bf[f] = *(const hf8*)&Bs[(wc * 64 + f * 16 + lr) * 72 + ko];
      }
#pragma unroll
      for (int fm = 0; fm < 4; ++fm)
#pragma unroll
        for (int fn = 0; fn < 4; ++fn)
          acc[fm][fn] = __builtin_amdgcn_mfma_f32_16x16x32_f16(
              af[fm], bf[fn], acc[fm][fn], 0, 0, 0);
    }
  }

  float bcol[4];
#pragma unroll
  for (int fn = 0; fn < 4; ++fn) bcol[fn] = bl[nc0 + wc * 64 + fn * 16 + lr];
  float sp[4] = {0.f, 0.f, 0.f, 0.f}, qp[4] = {0.f, 0.f, 0.f, 0.f};
#pragma unroll
  for (int fm = 0; fm < 4; ++fm)
#pragma unroll
    for (int fn = 0; fn < 4; ++fn) {
      int cl = wc * 64 + fn * 16 + lr;
#pragma unroll
      for (int j = 0; j < 4; ++j) {
        int rl = wr * 64 + fm * 16 + lk * 4 + j;
        float v = acc[fm][fn][j] + bcol[fn];
        Y16[(long)(row0 + rl) * 256 + nc0 + cl] = f2h(v);
        sp[fn] += v; qp[fn] += v * v;
      }
    }
#pragma unroll
  for (int fn = 0; fn < 4; ++fn) {
    sp[fn] += __shfl_xor(sp[fn], 16);
    sp[fn] += __shfl_xor(sp[fn], 32);
    qp[fn] += __shfl_xor(qp[fn], 16);
    qp[fn] += __shfl_xor(qp[fn], 32);
  }
  if (lk == 0) {
#pragma unroll
    for (int fn = 0; fn < 4; ++fn) {
      red_s[w * 64 + fn * 16 + lr] = sp[fn];
      red_q[w * 64 + fn * 16 + lr] = qp[fn];
    }
  }
  __syncthreads();
  if (t < 128) {
    float s = red_s[t] + red_s[128 + t];
    float q = red_q[t] + red_q[128 + t];
    float* p = Pp + (bm * 2 + bn) * 256;
    p[t] = s;
    p[128 + t] = q;
  }
}

// ------------------------------------------- BN stats reduce + finalize (1 block)
__global__ __launch_bounds__(256) void stats_finalize_k(
    const float* __restrict__ Pp, const float* __restrict__ bl,
    const float* __restrict__ gamma, const float* __restrict__ beta,
    float* __restrict__ scale, float* __restrict__ shiftv)
{
  int c = threadIdx.x;
  int half = c >> 7, cl = c & 127;
  float s = 0.f, s2 = 0.f;
  for (int bm = 0; bm < MTILES; ++bm) {
    const float* p = Pp + (bm * 2 + half) * 256;
    s += p[cl];
    s2 += p[128 + cl];
  }
  float bc = bl[c];
  s -= (float)(N_PAD - N_NODESC) * bc;
  s2 -= (float)(N_PAD - N_NODESC) * bc * bc;
  const float invN = 1.0f / (float)N_NODESC;
  float mu = s * invN;
  float var = s2 * invN - mu * mu;
  float rs = rsqrtf(var + 1e-5f);
  float sc = gamma[c] * rs;
  scale[c] = sc;
  shiftv[c] = beta[c] - mu * sc;
}

// ---------------------------------------------------------------- mean pooling
__device__ __forceinline__ int lower_bound_g(const int* gid, int n, int g)
{
  int lo = 0, hi = n;
  while (lo < hi) {
    int mid = (lo + hi) >> 1;
    if (gid[mid] < g) lo = mid + 1; else hi = mid;
  }
  return lo;
}

// 1 block/graph, 8 waves stride rows; BN+relu applied inline (layer-4 params).
__global__ __launch_bounds__(512) void pool_k(
    const unsigned short* __restrict__ Y16, const int* __restrict__ gid,
    const float* __restrict__ scale, const float* __restrict__ shiftv,
    float* __restrict__ gpool)
{
  __shared__ float red[8 * 256];
  int g = blockIdx.x;
  int lo = lower_bound_g(gid, N_NODESC, g);
  int hi = lower_bound_g(gid, N_NODESC, g + 1);
  int t = threadIdx.x;
  int w = t >> 6, lane = t & 63;
  int col = lane * 4;
  float4 sc = *(const float4*)(scale + col);
  float4 sh = *(const float4*)(shiftv + col);
  float a0 = 0.f, a1 = 0.f, a2 = 0.f, a3 = 0.f;
  for (int r = lo + w; r < hi; r += 8) {
    ushort4 u = *(const ushort4*)(Y16 + (long)r * 256 + col);
    a0 += fmaxf(0.f, h2f(u.x) * sc.x + sh.x);
    a1 += fmaxf(0.f, h2f(u.y) * sc.y + sh.y);
    a2 += fmaxf(0.f, h2f(u.z) * sc.z + sh.z);
    a3 += fmaxf(0.f, h2f(u.w) * sc.w + sh.w);
  }
  *(float4*)&red[w * 256 + col] = make_float4(a0, a1, a2, a3);
  __syncthreads();
  if (t < 256) {
    float s = 0.f;
#pragma unroll
    for (int j = 0; j < 8; ++j) s += red[j * 256 + t];
    int c = hi - lo;
    gpool[g * 256 + t] = s / (float)(c > 0 ? c : 1);
  }
}

// ---------------------------------------------------------------- final proj
__global__ __launch_bounds__(128) void final_k(
    const float* __restrict__ gpool, const float* __restrict__ Wp,
    const float* __restrict__ bp, float* __restrict__ out)
{
  __shared__ float gr[256];
  int g = blockIdx.x, t = threadIdx.x;
  gr[t] = gpool[g * 256 + t];
  gr[t + 128] = gpool[g * 256 + t + 128];
  __syncthreads();
  float acc = bp[t];
#pragma unroll 8
  for (int k = 0; k < 256; ++k) acc += gr[k] * Wp[k * 128 + t];
  out[g * 128 + t] = acc;
}

// ---------------------------------------------------------------- launcher
extern "C" void kernel_launch(void* const* d_in, const int* in_sizes, int n_in,
                              void* d_out, int out_size, void* d_ws, size_t ws_size,
                              hipStream_t stream)
{
  (void)in_sizes; (void)n_in; (void)out_size; (void)ws_size;
  const int* nfeat = (const int*)d_in[0];
  const int* efeat = (const int*)d_in[1];
  const int* src = (const int*)d_in[2];
  const int* dst = (const int*)d_in[3];
  const int* gid = (const int*)d_in[4];
  const float* atom_emb = (const float*)d_in[5];
  const float* edge_emb = (const float*)d_in[6];
  const float* W = (const float*)d_in[7];
  const float* b = (const float*)d_in[8];
  const float* gamma = (const float*)d_in[9];
  const float* beta = (const float*)d_in[10];
  const float* Wp = (const float*)d_in[11];
  const float* bp = (const float*)d_in[12];
  float* out = (float*)d_out;

  char* ws = (char*)d_ws;
  unsigned short* h16 = (unsigned short*)ws; ws += (size_t)N_PAD * 512;
  unsigned short* Y16 = (unsigned short*)ws; ws += (size_t)N_PAD * 512;
  unsigned short* X16 = (unsigned short*)ws; ws += (size_t)N_PAD * 512;
  unsigned short* Wt = (unsigned short*)ws; ws += 5 * 65536 * 2;
  int* csrc = (int*)ws; ws += 3200000;
  int* ceid = (int*)ws; ws += 3200000;
  int* row_start = (int*)ws; ws += 200064;
  int* degs_i = (int*)ws; ws += 200064;
  int* fill = (int*)ws; ws += 200064;
  int* cnt = (int*)ws; ws += 4800000;
  float* Pp = (float*)ws; ws += MTILES * 2 * 256 * 4;
  float* scale = (float*)ws; ws += 1024;
  float* shiftv = (float*)ws; ws += 1024;
  float* gpool = (float*)ws; ws += 131072;

  hipMemsetAsync(degs_i, 0, 200000, stream);
  hipMemsetAsync(fill, 0, 200000, stream);
  // zero X pad rows so GEMM pad output is exactly b[c]
  hipMemsetAsync(X16 + (size_t)N_NODESC * 256, 0,
                 (size_t)(N_PAD - N_NODESC) * 512, stream);

  wprep_k<<<1280, 256, 0, stream>>>(W, Wt);
  atom_encode_k<<<12500, 256, 0, stream>>>(nfeat, atom_emb, h16);
  deg_k<<<3125, 256, 0, stream>>>(dst, degs_i);
  scan_k<<<1, 1024, 0, stream>>>(degs_i, row_start, N_NODESC);
  scatter_k<<<3125, 256, 0, stream>>>(src, dst, row_start, fill, csrc, ceid);
  cnt_k<<<196, 256, 0, stream>>>(ceid, row_start, efeat, cnt);

  // layer 0 aggregate: atom-encoded h16, no BN
  aggregate_t<0><<<12500, 256, 0, stream>>>(h16, edge_emb, csrc, row_start,
                                            cnt, nullptr, nullptr, X16);
  for (int l = 0; l < 5; ++l) {
    gemm_k<<<dim3(MTILES, 2), 256, 0, stream>>>(X16, Wt + l * 65536, b + l * 256,
                                                Y16, Pp);
    stats_finalize_k<<<1, 256, 0, stream>>>(Pp, b + l * 256, gamma + l * 256,
                                            beta + l * 256, scale, shiftv);
    if (l < 4)
      aggregate_t<1><<<12500, 256, 0, stream>>>(Y16, edge_emb + (l + 1) * 6144,
                                                csrc, row_start, cnt, scale,
                                                shiftv, X16);
  }

  pool_k<<<128, 512, 0, stream>>>(Y16, gid, scale, shiftv, gpool);
  final_k<<<128, 128, 0, stream>>>(gpool, Wp, bp, out);
}

// Round 8
// 948.863 us; speedup vs baseline: 1.2263x; 1.2263x over previous
//
#include <hip/hip_runtime.h>

#define N_NODESC 50000
#define N_PAD 50176          // 392 * 128
#define N_EDGESC 800000
#define N_GRAPHSC 128
#define EMBEDC 256
#define MTILES 392

typedef __attribute__((ext_vector_type(8))) _Float16 hf8;
typedef __attribute__((ext_vector_type(4))) float fx4;

__device__ __forceinline__ float h2f(unsigned short u) {
  _Float16 h = *(_Float16*)&u;
  return (float)h;
}
__device__ __forceinline__ unsigned short f2h(float f) {
  _Float16 h = (_Float16)f;
  return *(unsigned short*)&h;
}
__device__ __forceinline__ unsigned int packh2(float lo, float hi) {
  return (unsigned int)f2h(lo) | ((unsigned int)f2h(hi) << 16);
}

// ---------------------------------------------------------------- atom encoder
__global__ __launch_bounds__(256) void atom_encode_k(
    const int* __restrict__ nfeat, const float* __restrict__ atom_emb,
    unsigned short* __restrict__ h16)
{
  int w = threadIdx.x >> 6, lane = threadIdx.x & 63;
  int n = blockIdx.x * 4 + w;
  if (n >= N_NODESC) return;
  const int* nf = nfeat + n * 9;
  float ax = 0.f, ay = 0.f, az = 0.f, aw = 0.f;
#pragma unroll
  for (int c = 0; c < 9; ++c) {
    int idx = nf[c];
    const float4* row = (const float4*)(atom_emb + (c * 128 + idx) * EMBEDC);
    float4 v = row[lane];
    ax += v.x; ay += v.y; az += v.z; aw += v.w;
  }
  ushort4 o;
  o.x = f2h(ax); o.y = f2h(ay); o.z = f2h(az); o.w = f2h(aw);
  *(ushort4*)(h16 + (long)n * 256 + lane * 4) = o;
}

// ---------------------------------------------------------------- degree count
__global__ __launch_bounds__(256) void deg_k(
    const int* __restrict__ dst, int* __restrict__ degs)
{
  int e = blockIdx.x * 256 + threadIdx.x;
  if (e >= N_EDGESC) return;
  atomicAdd(&degs[dst[e]], 1);
}

// ---------------------------------------------------------------- exclusive scan
__global__ __launch_bounds__(1024) void scan_k(
    const int* __restrict__ deg, int* __restrict__ row_start, int n)
{
  __shared__ int buf[1024];
  __shared__ int carry;
  int t = threadIdx.x;
  if (t == 0) carry = 0;
  __syncthreads();
  for (int base = 0; base < n; base += 8192) {
    int loc[8];
    int s = 0;
    int idx0 = base + t * 8;
#pragma unroll
    for (int i = 0; i < 8; ++i) {
      int v = (idx0 + i < n) ? deg[idx0 + i] : 0;
      loc[i] = v; s += v;
    }
    buf[t] = s;
    __syncthreads();
    for (int off = 1; off < 1024; off <<= 1) {
      int add = (t >= off) ? buf[t - off] : 0;
      __syncthreads();
      buf[t] += add;
      __syncthreads();
    }
    int excl = buf[t] - s;
    int run = carry + excl;
#pragma unroll
    for (int i = 0; i < 8; ++i) {
      if (idx0 + i < n) row_start[idx0 + i] = run;
      run += loc[i];
    }
    __syncthreads();
    if (t == 1023) carry += buf[1023];
    __syncthreads();
  }
  if (t == 0) row_start[n] = carry;
}

// ---------------------------------------------------------------- CSR scatter
__global__ __launch_bounds__(256) void scatter_k(
    const int* __restrict__ src, const int* __restrict__ dst,
    const int* __restrict__ row_start, int* __restrict__ fill,
    int* __restrict__ csrc, int* __restrict__ ceid)
{
  int e = blockIdx.x * 256 + threadIdx.x;
  if (e >= N_EDGESC) return;
  int d = dst[e];
  int pos = row_start[d] + atomicAdd(&fill[d], 1);
  csrc[pos] = src[e];
  ceid[pos] = e;
}

// ------------------------------------------ per-node edge-feature histogram
__global__ __launch_bounds__(256) void cnt_k(
    const int* __restrict__ ceid, const int* __restrict__ row_start,
    const int* __restrict__ efeat, int* __restrict__ cnt)
{
  __shared__ int lc[256 * 25];
  int t = threadIdx.x;
  int n = blockIdx.x * 256 + t;
  int base = t * 25;
#pragma unroll
  for (int j = 0; j < 24; ++j) lc[base + j] = 0;
  if (n >= N_NODESC) return;
  int s0 = row_start[n], s1 = row_start[n + 1];
  for (int e = s0; e < s1; ++e) {
    int eid = ceid[e];
    int v0 = efeat[eid * 3 + 0];
    int v1 = efeat[eid * 3 + 1];
    int v2 = efeat[eid * 3 + 2];
    lc[base + v0]++;
    lc[base + 8 + v1]++;
    lc[base + 16 + v2]++;
  }
#pragma unroll
  for (int j = 0; j < 24; ++j) cnt[n * 24 + j] = lc[base + j];
}

// ------------------------------------------------ W transpose + fp16 convert
__global__ __launch_bounds__(256) void wprep_k(
    const float* __restrict__ W, unsigned short* __restrict__ Wt)
{
  int tid = blockIdx.x * 256 + threadIdx.x;     // 5*65536
  int l = tid >> 16, r = tid & 65535;
  int n = r >> 8, k = r & 255;
  float w = W[(long)l * 65536 + k * 256 + n];
  Wt[tid] = f2h(w);                             // tid == l*65536 + n*256 + k
}

// ---------------------------------------------------------------- aggregation
// wave = 1 node; half-wave (32 lanes x 16B) covers a full 512B row.
// half 0 owns edges [s0, s0+ceil(d/2)) + self, half 1 owns the rest.
// FUSE_BN: gathered rows are pre-BN Y16; apply relu(y*sc+sh) with packed
// fp16 FMA/max (v_pk_*_f16) to keep VGPR below the 64-reg occupancy cliff.
template<int FUSE_BN>
__device__ __forceinline__ void bnacc(const uint4 u, float* a,
                                      const hf8 scv, const hf8 shv)
{
  union { uint4 u4; hf8 h8; } cv;
  cv.u4 = u;
  hf8 y = cv.h8;
  if (FUSE_BN) {
    y = y * scv + shv;                       // v_pk_fma_f16 x4
    y = __builtin_elementwise_max(y, (hf8)0);// v_pk_max_f16 x4
  }
#pragma unroll
  for (int k = 0; k < 8; ++k) a[k] += (float)y[k];
}

template<int FUSE_BN>
__global__ __launch_bounds__(256) void aggregate_t(
    const unsigned short* __restrict__ src16, const float* __restrict__ emb_l,
    const int* __restrict__ csrc, const int* __restrict__ row_start,
    const int* __restrict__ cnt, const float* __restrict__ scale,
    const float* __restrict__ shiftv, unsigned short* __restrict__ X16)
{
  __shared__ unsigned short semb[24 * EMBEDC];   // fp16, 12.3 KB
  for (int i = threadIdx.x; i < 24 * 128; i += 256) {
    float2 f = *(const float2*)&emb_l[i * 2];
    *(unsigned int*)&semb[i * 2] = packh2(f.x, f.y);
  }
  __syncthreads();
  int w = threadIdx.x >> 6, lane = threadIdx.x & 63;
  int n = blockIdx.x * 4 + w;          // 12500*4 == 50000 exactly
  int half = lane >> 5;
  int c8 = (lane & 31) * 8;
  hf8 scv = (hf8)0, shv = (hf8)0;
  if (FUSE_BN) {
#pragma unroll
    for (int k = 0; k < 8; ++k) {
      scv[k] = (_Float16)scale[c8 + k];
      shv[k] = (_Float16)shiftv[c8 + k];
    }
  }
  float a[8] = {0.f, 0.f, 0.f, 0.f, 0.f, 0.f, 0.f, 0.f};
  int s0 = row_start[n], s1 = row_start[n + 1];
  int d = s1 - s0;
  int dh0 = (d + 1) >> 1;
  int e = half ? (s0 + dh0) : s0;
  int rhi = half ? s1 : (s0 + dh0);
  if (half == 0) {                     // self row
    uint4 u = *(const uint4*)(src16 + (long)n * 256 + c8);
    bnacc<FUSE_BN>(u, a, scv, shv);
  }
  for (; e + 3 < rhi; e += 4) {
    int i0 = csrc[e], i1 = csrc[e + 1], i2 = csrc[e + 2], i3 = csrc[e + 3];
    uint4 u0 = *(const uint4*)(src16 + (long)i0 * 256 + c8);
    uint4 u1 = *(const uint4*)(src16 + (long)i1 * 256 + c8);
    uint4 u2 = *(const uint4*)(src16 + (long)i2 * 256 + c8);
    uint4 u3 = *(const uint4*)(src16 + (long)i3 * 256 + c8);
    bnacc<FUSE_BN>(u0, a, scv, shv); bnacc<FUSE_BN>(u1, a, scv, shv);
    bnacc<FUSE_BN>(u2, a, scv, shv); bnacc<FUSE_BN>(u3, a, scv, shv);
  }
  for (; e < rhi; ++e) {
    uint4 u = *(const uint4*)(src16 + (long)csrc[e] * 256 + c8);
    bnacc<FUSE_BN>(u, a, scv, shv);
  }
  // combine halves (lane l and l^32 hold the same 8 columns)
#pragma unroll
  for (int k = 0; k < 8; ++k) a[k] += __shfl_xor(a[k], 32);
  const int* cn = cnt + n * 24;
#pragma unroll
  for (int j = 0; j < 24; ++j) {
    int cj = cn[j];
    if (cj) {
      float fc = (float)cj;
      uint4 up = *(const uint4*)&semb[j * EMBEDC + c8];   // 16B/lane, conflict-free
      unsigned int wsv[4] = {up.x, up.y, up.z, up.w};
#pragma unroll
      for (int q = 0; q < 4; ++q) {
        a[2 * q]     += fc * h2f((unsigned short)(wsv[q] & 0xFFFF));
        a[2 * q + 1] += fc * h2f((unsigned short)(wsv[q] >> 16));
      }
    }
  }
  if (half == 0) {
    float inv = 1.0f / (float)(d + 1);
    uint4 o;
    o.x = packh2(a[0] * inv, a[1] * inv);
    o.y = packh2(a[2] * inv, a[3] * inv);
    o.z = packh2(a[4] * inv, a[5] * inv);
    o.w = packh2(a[6] * inv, a[7] * inv);
    *(uint4*)(X16 + (long)n * 256 + c8) = o;
  }
}

// ---------------------------------------------------------------- MFMA GEMM fp16
// Y16 = fp16(X @ W + b) ; per-block BN partials from fp32 accs (no atomics)
__global__ __launch_bounds__(256) void gemm_k(
    const unsigned short* __restrict__ X16, const unsigned short* __restrict__ Bt,
    const float* __restrict__ bl, unsigned short* __restrict__ Y16,
    float* __restrict__ Pp)
{
  __shared__ unsigned short As[128 * 72];
  __shared__ unsigned short Bs[128 * 72];
  __shared__ float red_s[256];
  __shared__ float red_q[256];

  int t = threadIdx.x;
  int bm = blockIdx.x, bn = blockIdx.y;
  int row0 = bm * 128, nc0 = bn * 128;
  int w = t >> 6, l = t & 63;
  int wr = w >> 1, wc = w & 1;
  int lr = l & 15, lk = l >> 4;

  fx4 acc[4][4];
#pragma unroll
  for (int i = 0; i < 4; ++i)
#pragma unroll
    for (int j = 0; j < 4; ++j) acc[i][j] = (fx4){0.f, 0.f, 0.f, 0.f};

  for (int kc = 0; kc < 256; kc += 64) {
    __syncthreads();
#pragma unroll
    for (int q = 0; q < 2; ++q) {
      int id = q * 256 + t;
      int r = id >> 2, c8 = (id & 3) * 16;
      long gA = (long)(row0 + r) * 256 + kc + c8;
      long gB = (long)(nc0 + r) * 256 + kc + c8;
      *(uint4*)&As[r * 72 + c8] = *(const uint4*)(X16 + gA);
      *(uint4*)&As[r * 72 + c8 + 8] = *(const uint4*)(X16 + gA + 8);
      *(uint4*)&Bs[r * 72 + c8] = *(const uint4*)(Bt + gB);
      *(uint4*)&Bs[r * 72 + c8 + 8] = *(const uint4*)(Bt + gB + 8);
    }
    __syncthreads();
#pragma unroll
    for (int ks = 0; ks < 2; ++ks) {
      int ko = ks * 32 + lk * 8;
      hf8 af[4], bf[4];
#pragma unroll
      for (int f = 0; f < 4; ++f) {
        af[f] = *(const hf8*)&As[(wr * 64 + f * 16 + lr) * 72 + ko];
        bf[f] = *(const hf8*)&Bs[(wc * 64 + f * 16 + lr) * 72 + ko];
      }
#pragma unroll
      for (int fm = 0; fm < 4; ++fm)
#pragma unroll
        for (int fn = 0; fn < 4; ++fn)
          acc[fm][fn] = __builtin_amdgcn_mfma_f32_16x16x32_f16(
              af[fm], bf[fn], acc[fm][fn], 0, 0, 0);
    }
  }

  float bcol[4];
#pragma unroll
  for (int fn = 0; fn < 4; ++fn) bcol[fn] = bl[nc0 + wc * 64 + fn * 16 + lr];
  float sp[4] = {0.f, 0.f, 0.f, 0.f}, qp[4] = {0.f, 0.f, 0.f, 0.f};
#pragma unroll
  for (int fm = 0; fm < 4; ++fm)
#pragma unroll
    for (int fn = 0; fn < 4; ++fn) {
      int cl = wc * 64 + fn * 16 + lr;
#pragma unroll
      for (int j = 0; j < 4; ++j) {
        int rl = wr * 64 + fm * 16 + lk * 4 + j;
        float v = acc[fm][fn][j] + bcol[fn];
        Y16[(long)(row0 + rl) * 256 + nc0 + cl] = f2h(v);
        sp[fn] += v; qp[fn] += v * v;
      }
    }
#pragma unroll
  for (int fn = 0; fn < 4; ++fn) {
    sp[fn] += __shfl_xor(sp[fn], 16);
    sp[fn] += __shfl_xor(sp[fn], 32);
    qp[fn] += __shfl_xor(qp[fn], 16);
    qp[fn] += __shfl_xor(qp[fn], 32);
  }
  if (lk == 0) {
#pragma unroll
    for (int fn = 0; fn < 4; ++fn) {
      red_s[w * 64 + fn * 16 + lr] = sp[fn];
      red_q[w * 64 + fn * 16 + lr] = qp[fn];
    }
  }
  __syncthreads();
  if (t < 128) {
    float s = red_s[t] + red_s[128 + t];
    float q = red_q[t] + red_q[128 + t];
    float* p = Pp + (bm * 2 + bn) * 256;
    p[t] = s;
    p[128 + t] = q;
  }
}

// ------------------------------------------- BN stats reduce + finalize (1 block)
__global__ __launch_bounds__(256) void stats_finalize_k(
    const float* __restrict__ Pp, const float* __restrict__ bl,
    const float* __restrict__ gamma, const float* __restrict__ beta,
    float* __restrict__ scale, float* __restrict__ shiftv)
{
  int c = threadIdx.x;
  int half = c >> 7, cl = c & 127;
  float s = 0.f, s2 = 0.f;
  for (int bm = 0; bm < MTILES; ++bm) {
    const float* p = Pp + (bm * 2 + half) * 256;
    s += p[cl];
    s2 += p[128 + cl];
  }
  float bc = bl[c];
  s -= (float)(N_PAD - N_NODESC) * bc;
  s2 -= (float)(N_PAD - N_NODESC) * bc * bc;
  const float invN = 1.0f / (float)N_NODESC;
  float mu = s * invN;
  float var = s2 * invN - mu * mu;
  float rs = rsqrtf(var + 1e-5f);
  float sc = gamma[c] * rs;
  scale[c] = sc;
  shiftv[c] = beta[c] - mu * sc;
}

// ---------------------------------------------------------------- mean pooling
__device__ __forceinline__ int lower_bound_g(const int* gid, int n, int g)
{
  int lo = 0, hi = n;
  while (lo < hi) {
    int mid = (lo + hi) >> 1;
    if (gid[mid] < g) lo = mid + 1; else hi = mid;
  }
  return lo;
}

// 1 block/graph, 8 waves stride rows; BN+relu applied inline (layer-4 params).
__global__ __launch_bounds__(512) void pool_k(
    const unsigned short* __restrict__ Y16, const int* __restrict__ gid,
    const float* __restrict__ scale, const float* __restrict__ shiftv,
    float* __restrict__ gpool)
{
  __shared__ float red[8 * 256];
  int g = blockIdx.x;
  int lo = lower_bound_g(gid, N_NODESC, g);
  int hi = lower_bound_g(gid, N_NODESC, g + 1);
  int t = threadIdx.x;
  int w = t >> 6, lane = t & 63;
  int col = lane * 4;
  float4 sc = *(const float4*)(scale + col);
  float4 sh = *(const float4*)(shiftv + col);
  float a0 = 0.f, a1 = 0.f, a2 = 0.f, a3 = 0.f;
  for (int r = lo + w; r < hi; r += 8) {
    ushort4 u = *(const ushort4*)(Y16 + (long)r * 256 + col);
    a0 += fmaxf(0.f, h2f(u.x) * sc.x + sh.x);
    a1 += fmaxf(0.f, h2f(u.y) * sc.y + sh.y);
    a2 += fmaxf(0.f, h2f(u.z) * sc.z + sh.z);
    a3 += fmaxf(0.f, h2f(u.w) * sc.w + sh.w);
  }
  *(float4*)&red[w * 256 + col] = make_float4(a0, a1, a2, a3);
  __syncthreads();
  if (t < 256) {
    float s = 0.f;
#pragma unroll
    for (int j = 0; j < 8; ++j) s += red[j * 256 + t];
    int c = hi - lo;
    gpool[g * 256 + t] = s / (float)(c > 0 ? c : 1);
  }
}

// ---------------------------------------------------------------- final proj
__global__ __launch_bounds__(128) void final_k(
    const float* __restrict__ gpool, const float* __restrict__ Wp,
    const float* __restrict__ bp, float* __restrict__ out)
{
  __shared__ float gr[256];
  int g = blockIdx.x, t = threadIdx.x;
  gr[t] = gpool[g * 256 + t];
  gr[t + 128] = gpool[g * 256 + t + 128];
  __syncthreads();
  float acc = bp[t];
#pragma unroll 8
  for (int k = 0; k < 256; ++k) acc += gr[k] * Wp[k * 128 + t];
  out[g * 128 + t] = acc;
}

// ---------------------------------------------------------------- launcher
extern "C" void kernel_launch(void* const* d_in, const int* in_sizes, int n_in,
                              void* d_out, int out_size, void* d_ws, size_t ws_size,
                              hipStream_t stream)
{
  (void)in_sizes; (void)n_in; (void)out_size; (void)ws_size;
  const int* nfeat = (const int*)d_in[0];
  const int* efeat = (const int*)d_in[1];
  const int* src = (const int*)d_in[2];
  const int* dst = (const int*)d_in[3];
  const int* gid = (const int*)d_in[4];
  const float* atom_emb = (const float*)d_in[5];
  const float* edge_emb = (const float*)d_in[6];
  const float* W = (const float*)d_in[7];
  const float* b = (const float*)d_in[8];
  const float* gamma = (const float*)d_in[9];
  const float* beta = (const float*)d_in[10];
  const float* Wp = (const float*)d_in[11];
  const float* bp = (const float*)d_in[12];
  float* out = (float*)d_out;

  char* ws = (char*)d_ws;
  unsigned short* h16 = (unsigned short*)ws; ws += (size_t)N_PAD * 512;
  unsigned short* Y16 = (unsigned short*)ws; ws += (size_t)N_PAD * 512;
  unsigned short* X16 = (unsigned short*)ws; ws += (size_t)N_PAD * 512;
  unsigned short* Wt = (unsigned short*)ws; ws += 5 * 65536 * 2;
  int* csrc = (int*)ws; ws += 3200000;
  int* ceid = (int*)ws; ws += 3200000;
  int* row_start = (int*)ws; ws += 200064;
  int* degs_i = (int*)ws; ws += 200064;
  int* fill = (int*)ws; ws += 200064;
  int* cnt = (int*)ws; ws += 4800000;
  float* Pp = (float*)ws; ws += MTILES * 2 * 256 * 4;
  float* scale = (float*)ws; ws += 1024;
  float* shiftv = (float*)ws; ws += 1024;
  float* gpool = (float*)ws; ws += 131072;

  hipMemsetAsync(degs_i, 0, 200000, stream);
  hipMemsetAsync(fill, 0, 200000, stream);
  // zero X pad rows so GEMM pad output is exactly b[c]
  hipMemsetAsync(X16 + (size_t)N_NODESC * 256, 0,
                 (size_t)(N_PAD - N_NODESC) * 512, stream);

  wprep_k<<<1280, 256, 0, stream>>>(W, Wt);
  atom_encode_k<<<12500, 256, 0, stream>>>(nfeat, atom_emb, h16);
  deg_k<<<3125, 256, 0, stream>>>(dst, degs_i);
  scan_k<<<1, 1024, 0, stream>>>(degs_i, row_start, N_NODESC);
  scatter_k<<<3125, 256, 0, stream>>>(src, dst, row_start, fill, csrc, ceid);
  cnt_k<<<196, 256, 0, stream>>>(ceid, row_start, efeat, cnt);

  // layer 0 aggregate: atom-encoded h16, no BN
  aggregate_t<0><<<12500, 256, 0, stream>>>(h16, edge_emb, csrc, row_start,
                                            cnt, nullptr, nullptr, X16);
  for (int l = 0; l < 5; ++l) {
    gemm_k<<<dim3(MTILES, 2), 256, 0, stream>>>(X16, Wt + l * 65536, b + l * 256,
                                                Y16, Pp);
    stats_finalize_k<<<1, 256, 0, stream>>>(Pp, b + l * 256, gamma + l * 256,
                                            beta + l * 256, scale, shiftv);
    if (l < 4)
      aggregate_t<1><<<12500, 256, 0, stream>>>(Y16, edge_emb + (l + 1) * 6144,
                                                csrc, row_start, cnt, scale,
                                                shiftv, X16);
  }

  pool_k<<<128, 512, 0, stream>>>(Y16, gid, scale, shiftv, gpool);
  final_k<<<128, 128, 0, stream>>>(gpool, Wp, bp, out);
}

// Round 9
// 926.184 us; speedup vs baseline: 1.2563x; 1.0245x over previous
//
#include <hip/hip_runtime.h>

#define N_NODESC 50000
#define N_PAD 50176          // 392 * 128
#define N_EDGESC 800000
#define N_GRAPHSC 128
#define EMBEDC 256
#define MTILES 392

typedef __attribute__((ext_vector_type(8))) _Float16 hf8;
typedef __attribute__((ext_vector_type(4))) float fx4;

__device__ __forceinline__ float h2f(unsigned short u) {
  _Float16 h = *(_Float16*)&u;
  return (float)h;
}
__device__ __forceinline__ unsigned short f2h(float f) {
  _Float16 h = (_Float16)f;
  return *(unsigned short*)&h;
}
__device__ __forceinline__ unsigned int packh2(float lo, float hi) {
  return (unsigned int)f2h(lo) | ((unsigned int)f2h(hi) << 16);
}

// ---------------------------------------------------------------- atom encoder
__global__ __launch_bounds__(256) void atom_encode_k(
    const int* __restrict__ nfeat, const float* __restrict__ atom_emb,
    unsigned short* __restrict__ h16)
{
  int w = threadIdx.x >> 6, lane = threadIdx.x & 63;
  int n = blockIdx.x * 4 + w;
  if (n >= N_NODESC) return;
  const int* nf = nfeat + n * 9;
  float ax = 0.f, ay = 0.f, az = 0.f, aw = 0.f;
#pragma unroll
  for (int c = 0; c < 9; ++c) {
    int idx = nf[c];
    const float4* row = (const float4*)(atom_emb + (c * 128 + idx) * EMBEDC);
    float4 v = row[lane];
    ax += v.x; ay += v.y; az += v.z; aw += v.w;
  }
  ushort4 o;
  o.x = f2h(ax); o.y = f2h(ay); o.z = f2h(az); o.w = f2h(aw);
  *(ushort4*)(h16 + (long)n * 256 + lane * 4) = o;
}

// ---------------------------------------------------------------- degree count
__global__ __launch_bounds__(256) void deg_k(
    const int* __restrict__ dst, int* __restrict__ degs)
{
  int e = blockIdx.x * 256 + threadIdx.x;
  if (e >= N_EDGESC) return;
  atomicAdd(&degs[dst[e]], 1);
}

// ---------------------------------------------------------------- exclusive scan
__global__ __launch_bounds__(1024) void scan_k(
    const int* __restrict__ deg, int* __restrict__ row_start, int n)
{
  __shared__ int buf[1024];
  __shared__ int carry;
  int t = threadIdx.x;
  if (t == 0) carry = 0;
  __syncthreads();
  for (int base = 0; base < n; base += 8192) {
    int loc[8];
    int s = 0;
    int idx0 = base + t * 8;
#pragma unroll
    for (int i = 0; i < 8; ++i) {
      int v = (idx0 + i < n) ? deg[idx0 + i] : 0;
      loc[i] = v; s += v;
    }
    buf[t] = s;
    __syncthreads();
    for (int off = 1; off < 1024; off <<= 1) {
      int add = (t >= off) ? buf[t - off] : 0;
      __syncthreads();
      buf[t] += add;
      __syncthreads();
    }
    int excl = buf[t] - s;
    int run = carry + excl;
#pragma unroll
    for (int i = 0; i < 8; ++i) {
      if (idx0 + i < n) row_start[idx0 + i] = run;
      run += loc[i];
    }
    __syncthreads();
    if (t == 1023) carry += buf[1023];
    __syncthreads();
  }
  if (t == 0) row_start[n] = carry;
}

// ---------------------------------------------------------------- CSR scatter
__global__ __launch_bounds__(256) void scatter_k(
    const int* __restrict__ src, const int* __restrict__ dst,
    const int* __restrict__ row_start, int* __restrict__ fill,
    int* __restrict__ csrc, int* __restrict__ ceid)
{
  int e = blockIdx.x * 256 + threadIdx.x;
  if (e >= N_EDGESC) return;
  int d = dst[e];
  int pos = row_start[d] + atomicAdd(&fill[d], 1);
  csrc[pos] = src[e];
  ceid[pos] = e;
}

// ------------------------------------------ per-node edge-feature histogram
__global__ __launch_bounds__(256) void cnt_k(
    const int* __restrict__ ceid, const int* __restrict__ row_start,
    const int* __restrict__ efeat, int* __restrict__ cnt)
{
  __shared__ int lc[256 * 25];
  int t = threadIdx.x;
  int n = blockIdx.x * 256 + t;
  int base = t * 25;
#pragma unroll
  for (int j = 0; j < 24; ++j) lc[base + j] = 0;
  if (n >= N_NODESC) return;
  int s0 = row_start[n], s1 = row_start[n + 1];
  for (int e = s0; e < s1; ++e) {
    int eid = ceid[e];
    int v0 = efeat[eid * 3 + 0];
    int v1 = efeat[eid * 3 + 1];
    int v2 = efeat[eid * 3 + 2];
    lc[base + v0]++;
    lc[base + 8 + v1]++;
    lc[base + 16 + v2]++;
  }
#pragma unroll
  for (int j = 0; j < 24; ++j) cnt[n * 24 + j] = lc[base + j];
}

// ------------------------------------------------ W transpose + fp16 convert
__global__ __launch_bounds__(256) void wprep_k(
    const float* __restrict__ W, unsigned short* __restrict__ Wt)
{
  int tid = blockIdx.x * 256 + threadIdx.x;     // 5*65536
  int l = tid >> 16, r = tid & 65535;
  int n = r >> 8, k = r & 255;
  float w = W[(long)l * 65536 + k * 256 + n];
  Wt[tid] = f2h(w);                             // tid == l*65536 + n*256 + k
}

// ---------------------------------------------------------------- aggregation
// wave = 1 node; half-wave (32 lanes x 16B) covers a full 512B row.
// half 0 owns edges [s0, s0+ceil(d/2)) + self, half 1 owns the rest.
// FUSE_BN: gathered rows are pre-BN Y16; apply relu(y*sc+sh) with packed
// fp16 FMA/max; 6-deep unroll keeps ~6 gathers in flight at VGPR<48.
template<int FUSE_BN>
__device__ __forceinline__ void bnacc(const uint4 u, float* a,
                                      const hf8 scv, const hf8 shv)
{
  union { uint4 u4; hf8 h8; } cv;
  cv.u4 = u;
  hf8 y = cv.h8;
  if (FUSE_BN) {
    y = y * scv + shv;                       // v_pk_fma_f16 x4
    y = __builtin_elementwise_max(y, (hf8)0);// v_pk_max_f16 x4
  }
#pragma unroll
  for (int k = 0; k < 8; ++k) a[k] += (float)y[k];
}

template<int FUSE_BN>
__global__ __launch_bounds__(256) void aggregate_t(
    const unsigned short* __restrict__ src16, const float* __restrict__ emb_l,
    const int* __restrict__ csrc, const int* __restrict__ row_start,
    const int* __restrict__ cnt, const float* __restrict__ scale,
    const float* __restrict__ shiftv, unsigned short* __restrict__ X16)
{
  __shared__ unsigned short semb[24 * EMBEDC];   // fp16, 12.3 KB
  for (int i = threadIdx.x; i < 24 * 128; i += 256) {
    float2 f = *(const float2*)&emb_l[i * 2];
    *(unsigned int*)&semb[i * 2] = packh2(f.x, f.y);
  }
  __syncthreads();
  int w = threadIdx.x >> 6, lane = threadIdx.x & 63;
  int n = blockIdx.x * 4 + w;          // 12500*4 == 50000 exactly
  int half = lane >> 5;
  int c8 = (lane & 31) * 8;
  hf8 scv = (hf8)0, shv = (hf8)0;
  if (FUSE_BN) {
#pragma unroll
    for (int k = 0; k < 8; ++k) {
      scv[k] = (_Float16)scale[c8 + k];
      shv[k] = (_Float16)shiftv[c8 + k];
    }
  }
  float a[8] = {0.f, 0.f, 0.f, 0.f, 0.f, 0.f, 0.f, 0.f};
  int s0 = row_start[n], s1 = row_start[n + 1];
  int d = s1 - s0;
  int dh0 = (d + 1) >> 1;
  int e = half ? (s0 + dh0) : s0;
  int rhi = half ? s1 : (s0 + dh0);
  if (half == 0) {                     // self row
    uint4 u = *(const uint4*)(src16 + (long)n * 256 + c8);
    bnacc<FUSE_BN>(u, a, scv, shv);
  }
  for (; e + 5 < rhi; e += 6) {
    int i0 = csrc[e],     i1 = csrc[e + 1], i2 = csrc[e + 2];
    int i3 = csrc[e + 3], i4 = csrc[e + 4], i5 = csrc[e + 5];
    uint4 u0 = *(const uint4*)(src16 + (long)i0 * 256 + c8);
    uint4 u1 = *(const uint4*)(src16 + (long)i1 * 256 + c8);
    uint4 u2 = *(const uint4*)(src16 + (long)i2 * 256 + c8);
    uint4 u3 = *(const uint4*)(src16 + (long)i3 * 256 + c8);
    uint4 u4 = *(const uint4*)(src16 + (long)i4 * 256 + c8);
    uint4 u5 = *(const uint4*)(src16 + (long)i5 * 256 + c8);
    bnacc<FUSE_BN>(u0, a, scv, shv); bnacc<FUSE_BN>(u1, a, scv, shv);
    bnacc<FUSE_BN>(u2, a, scv, shv); bnacc<FUSE_BN>(u3, a, scv, shv);
    bnacc<FUSE_BN>(u4, a, scv, shv); bnacc<FUSE_BN>(u5, a, scv, shv);
  }
  if (e + 2 < rhi) {
    int i0 = csrc[e], i1 = csrc[e + 1], i2 = csrc[e + 2];
    uint4 u0 = *(const uint4*)(src16 + (long)i0 * 256 + c8);
    uint4 u1 = *(const uint4*)(src16 + (long)i1 * 256 + c8);
    uint4 u2 = *(const uint4*)(src16 + (long)i2 * 256 + c8);
    bnacc<FUSE_BN>(u0, a, scv, shv); bnacc<FUSE_BN>(u1, a, scv, shv);
    bnacc<FUSE_BN>(u2, a, scv, shv);
    e += 3;
  }
  for (; e < rhi; ++e) {
    uint4 u = *(const uint4*)(src16 + (long)csrc[e] * 256 + c8);
    bnacc<FUSE_BN>(u, a, scv, shv);
  }
  // combine halves (lane l and l^32 hold the same 8 columns)
#pragma unroll
  for (int k = 0; k < 8; ++k) a[k] += __shfl_xor(a[k], 32);
  const int* cn = cnt + n * 24;
#pragma unroll
  for (int j = 0; j < 24; ++j) {
    int cj = cn[j];
    if (cj) {
      float fc = (float)cj;
      uint4 up = *(const uint4*)&semb[j * EMBEDC + c8];   // 16B/lane, conflict-free
      unsigned int wsv[4] = {up.x, up.y, up.z, up.w};
#pragma unroll
      for (int q = 0; q < 4; ++q) {
        a[2 * q]     += fc * h2f((unsigned short)(wsv[q] & 0xFFFF));
        a[2 * q + 1] += fc * h2f((unsigned short)(wsv[q] >> 16));
      }
    }
  }
  if (half == 0) {
    float inv = 1.0f / (float)(d + 1);
    uint4 o;
    o.x = packh2(a[0] * inv, a[1] * inv);
    o.y = packh2(a[2] * inv, a[3] * inv);
    o.z = packh2(a[4] * inv, a[5] * inv);
    o.w = packh2(a[6] * inv, a[7] * inv);
    *(uint4*)(X16 + (long)n * 256 + c8) = o;
  }
}

// ---------------------------------------------------------------- MFMA GEMM fp16
// Y16 = fp16(X @ W + b) ; per-block BN partials from fp32 accs (no atomics)
__global__ __launch_bounds__(256) void gemm_k(
    const unsigned short* __restrict__ X16, const unsigned short* __restrict__ Bt,
    const float* __restrict__ bl, unsigned short* __restrict__ Y16,
    float* __restrict__ Pp)
{
  __shared__ unsigned short As[128 * 72];
  __shared__ unsigned short Bs[128 * 72];
  __shared__ float red_s[256];
  __shared__ float red_q[256];

  int t = threadIdx.x;
  int bm = blockIdx.x, bn = blockIdx.y;
  int row0 = bm * 128, nc0 = bn * 128;
  int w = t >> 6, l = t & 63;
  int wr = w >> 1, wc = w & 1;
  int lr = l & 15, lk = l >> 4;

  fx4 acc[4][4];
#pragma unroll
  for (int i = 0; i < 4; ++i)
#pragma unroll
    for (int j = 0; j < 4; ++j) acc[i][j] = (fx4){0.f, 0.f, 0.f, 0.f};

  for (int kc = 0; kc < 256; kc += 64) {
    __syncthreads();
#pragma unroll
    for (int q = 0; q < 2; ++q) {
      int id = q * 256 + t;
      int r = id >> 2, c8 = (id & 3) * 16;
      long gA = (long)(row0 + r) * 256 + kc + c8;
      long gB = (long)(nc0 + r) * 256 + kc + c8;
      *(uint4*)&As[r * 72 + c8] = *(const uint4*)(X16 + gA);
      *(uint4*)&As[r * 72 + c8 + 8] = *(const uint4*)(X16 + gA + 8);
      *(uint4*)&Bs[r * 72 + c8] = *(const uint4*)(Bt + gB);
      *(uint4*)&Bs[r * 72 + c8 + 8] = *(const uint4*)(Bt + gB + 8);
    }
    __syncthreads();
#pragma unroll
    for (int ks = 0; ks < 2; ++ks) {
      int ko = ks * 32 + lk * 8;
      hf8 af[4], bf[4];
#pragma unroll
      for (int f = 0; f < 4; ++f) {
        af[f] = *(const hf8*)&As[(wr * 64 + f * 16 + lr) * 72 + ko];
        bf[f] = *(const hf8*)&Bs[(wc * 64 + f * 16 + lr) * 72 + ko];
      }
#pragma unroll
      for (int fm = 0; fm < 4; ++fm)
#pragma unroll
        for (int fn = 0; fn < 4; ++fn)
          acc[fm][fn] = __builtin_amdgcn_mfma_f32_16x16x32_f16(
              af[fm], bf[fn], acc[fm][fn], 0, 0, 0);
    }
  }

  float bcol[4];
#pragma unroll
  for (int fn = 0; fn < 4; ++fn) bcol[fn] = bl[nc0 + wc * 64 + fn * 16 + lr];
  float sp[4] = {0.f, 0.f, 0.f, 0.f}, qp[4] = {0.f, 0.f, 0.f, 0.f};
#pragma unroll
  for (int fm = 0; fm < 4; ++fm)
#pragma unroll
    for (int fn = 0; fn < 4; ++fn) {
      int cl = wc * 64 + fn * 16 + lr;
#pragma unroll
      for (int j = 0; j < 4; ++j) {
        int rl = wr * 64 + fm * 16 + lk * 4 + j;
        float v = acc[fm][fn][j] + bcol[fn];
        Y16[(long)(row0 + rl) * 256 + nc0 + cl] = f2h(v);
        sp[fn] += v; qp[fn] += v * v;
      }
    }
#pragma unroll
  for (int fn = 0; fn < 4; ++fn) {
    sp[fn] += __shfl_xor(sp[fn], 16);
    sp[fn] += __shfl_xor(sp[fn], 32);
    qp[fn] += __shfl_xor(qp[fn], 16);
    qp[fn] += __shfl_xor(qp[fn], 32);
  }
  if (lk == 0) {
#pragma unroll
    for (int fn = 0; fn < 4; ++fn) {
      red_s[w * 64 + fn * 16 + lr] = sp[fn];
      red_q[w * 64 + fn * 16 + lr] = qp[fn];
    }
  }
  __syncthreads();
  if (t < 128) {
    float s = red_s[t] + red_s[128 + t];
    float q = red_q[t] + red_q[128 + t];
    float* p = Pp + (bm * 2 + bn) * 256;
    p[t] = s;
    p[128 + t] = q;
  }
}

// --------------------------- BN stats reduce + finalize (256 blocks, parallel)
__global__ __launch_bounds__(128) void stats_finalize_k(
    const float* __restrict__ Pp, const float* __restrict__ bl,
    const float* __restrict__ gamma, const float* __restrict__ beta,
    float* __restrict__ scale, float* __restrict__ shiftv)
{
  __shared__ float red_s[128];
  __shared__ float red_q[128];
  int c = blockIdx.x;                 // one column per block
  int half = c >> 7, cl = c & 127;
  int t = threadIdx.x;
  float s = 0.f, q = 0.f;
  for (int bm = t; bm < MTILES; bm += 128) {
    const float* p = Pp + (bm * 2 + half) * 256;
    s += p[cl];
    q += p[128 + cl];
  }
  red_s[t] = s; red_q[t] = q;
  __syncthreads();
#pragma unroll
  for (int off = 64; off > 0; off >>= 1) {
    if (t < off) {
      red_s[t] += red_s[t + off];
      red_q[t] += red_q[t + off];
    }
    __syncthreads();
  }
  if (t == 0) {
    s = red_s[0]; q = red_q[0];
    float bc = bl[c];
    s -= (float)(N_PAD - N_NODESC) * bc;
    q -= (float)(N_PAD - N_NODESC) * bc * bc;
    const float invN = 1.0f / (float)N_NODESC;
    float mu = s * invN;
    float var = q * invN - mu * mu;
    float rsq = rsqrtf(var + 1e-5f);
    float sc = gamma[c] * rsq;
    scale[c] = sc;
    shiftv[c] = beta[c] - mu * sc;
  }
}

// ---------------------------------------------------------------- mean pooling
__device__ __forceinline__ int lower_bound_g(const int* gid, int n, int g)
{
  int lo = 0, hi = n;
  while (lo < hi) {
    int mid = (lo + hi) >> 1;
    if (gid[mid] < g) lo = mid + 1; else hi = mid;
  }
  return lo;
}

// 1 block/graph, 8 waves stride rows; BN+relu applied inline (layer-4 params).
__global__ __launch_bounds__(512) void pool_k(
    const unsigned short* __restrict__ Y16, const int* __restrict__ gid,
    const float* __restrict__ scale, const float* __restrict__ shiftv,
    float* __restrict__ gpool)
{
  __shared__ float red[8 * 256];
  int g = blockIdx.x;
  int lo = lower_bound_g(gid, N_NODESC, g);
  int hi = lower_bound_g(gid, N_NODESC, g + 1);
  int t = threadIdx.x;
  int w = t >> 6, lane = t & 63;
  int col = lane * 4;
  float4 sc = *(const float4*)(scale + col);
  float4 sh = *(const float4*)(shiftv + col);
  float a0 = 0.f, a1 = 0.f, a2 = 0.f, a3 = 0.f;
  for (int r = lo + w; r < hi; r += 8) {
    ushort4 u = *(const ushort4*)(Y16 + (long)r * 256 + col);
    a0 += fmaxf(0.f, h2f(u.x) * sc.x + sh.x);
    a1 += fmaxf(0.f, h2f(u.y) * sc.y + sh.y);
    a2 += fmaxf(0.f, h2f(u.z) * sc.z + sh.z);
    a3 += fmaxf(0.f, h2f(u.w) * sc.w + sh.w);
  }
  *(float4*)&red[w * 256 + col] = make_float4(a0, a1, a2, a3);
  __syncthreads();
  if (t < 256) {
    float s = 0.f;
#pragma unroll
    for (int j = 0; j < 8; ++j) s += red[j * 256 + t];
    int c = hi - lo;
    gpool[g * 256 + t] = s / (float)(c > 0 ? c : 1);
  }
}

// ---------------------------------------------------------------- final proj
__global__ __launch_bounds__(128) void final_k(
    const float* __restrict__ gpool, const float* __restrict__ Wp,
    const float* __restrict__ bp, float* __restrict__ out)
{
  __shared__ float gr[256];
  int g = blockIdx.x, t = threadIdx.x;
  gr[t] = gpool[g * 256 + t];
  gr[t + 128] = gpool[g * 256 + t + 128];
  __syncthreads();
  float acc = bp[t];
#pragma unroll 8
  for (int k = 0; k < 256; ++k) acc += gr[k] * Wp[k * 128 + t];
  out[g * 128 + t] = acc;
}

// ---------------------------------------------------------------- launcher
extern "C" void kernel_launch(void* const* d_in, const int* in_sizes, int n_in,
                              void* d_out, int out_size, void* d_ws, size_t ws_size,
                              hipStream_t stream)
{
  (void)in_sizes; (void)n_in; (void)out_size; (void)ws_size;
  const int* nfeat = (const int*)d_in[0];
  const int* efeat = (const int*)d_in[1];
  const int* src = (const int*)d_in[2];
  const int* dst = (const int*)d_in[3];
  const int* gid = (const int*)d_in[4];
  const float* atom_emb = (const float*)d_in[5];
  const float* edge_emb = (const float*)d_in[6];
  const float* W = (const float*)d_in[7];
  const float* b = (const float*)d_in[8];
  const float* gamma = (const float*)d_in[9];
  const float* beta = (const float*)d_in[10];
  const float* Wp = (const float*)d_in[11];
  const float* bp = (const float*)d_in[12];
  float* out = (float*)d_out;

  char* ws = (char*)d_ws;
  unsigned short* h16 = (unsigned short*)ws; ws += (size_t)N_PAD * 512;
  unsigned short* Y16 = (unsigned short*)ws; ws += (size_t)N_PAD * 512;
  unsigned short* X16 = (unsigned short*)ws; ws += (size_t)N_PAD * 512;
  unsigned short* Wt = (unsigned short*)ws; ws += 5 * 65536 * 2;
  int* csrc = (int*)ws; ws += 3200000;
  int* ceid = (int*)ws; ws += 3200000;
  int* row_start = (int*)ws; ws += 200064;
  int* degs_i = (int*)ws; ws += 200064;
  int* fill = (int*)ws; ws += 200064;
  int* cnt = (int*)ws; ws += 4800000;
  float* Pp = (float*)ws; ws += MTILES * 2 * 256 * 4;
  float* scale = (float*)ws; ws += 1024;
  float* shiftv = (float*)ws; ws += 1024;
  float* gpool = (float*)ws; ws += 131072;

  hipMemsetAsync(degs_i, 0, 200000, stream);
  hipMemsetAsync(fill, 0, 200000, stream);
  // zero X pad rows so GEMM pad output is exactly b[c]
  hipMemsetAsync(X16 + (size_t)N_NODESC * 256, 0,
                 (size_t)(N_PAD - N_NODESC) * 512, stream);

  wprep_k<<<1280, 256, 0, stream>>>(W, Wt);
  atom_encode_k<<<12500, 256, 0, stream>>>(nfeat, atom_emb, h16);
  deg_k<<<3125, 256, 0, stream>>>(dst, degs_i);
  scan_k<<<1, 1024, 0, stream>>>(degs_i, row_start, N_NODESC);
  scatter_k<<<3125, 256, 0, stream>>>(src, dst, row_start, fill, csrc, ceid);
  cnt_k<<<196, 256, 0, stream>>>(ceid, row_start, efeat, cnt);

  // layer 0 aggregate: atom-encoded h16, no BN
  aggregate_t<0><<<12500, 256, 0, stream>>>(h16, edge_emb, csrc, row_start,
                                            cnt, nullptr, nullptr, X16);
  for (int l = 0; l < 5; ++l) {
    gemm_k<<<dim3(MTILES, 2), 256, 0, stream>>>(X16, Wt + l * 65536, b + l * 256,
                                                Y16, Pp);
    stats_finalize_k<<<256, 128, 0, stream>>>(Pp, b + l * 256, gamma + l * 256,
                                              beta + l * 256, scale, shiftv);
    if (l < 4)
      aggregate_t<1><<<12500, 256, 0, stream>>>(Y16, edge_emb + (l + 1) * 6144,
                                                csrc, row_start, cnt, scale,
                                                shiftv, X16);
  }

  pool_k<<<128, 512, 0, stream>>>(Y16, gid, scale, shiftv, gpool);
  final_k<<<128, 128, 0, stream>>>(gpool, Wp, bp, out);
}